// Round 1
// 299.484 us; speedup vs baseline: 1.0524x; 1.0524x over previous
//
#include <hip/hip_runtime.h>
#include <hip/hip_bf16.h>

#define IN_CH 128
#define HID 64
#define NEG_SLOPE 0.2f
#define BSH 9            // bucket = dst >> 9  (512 dsts per bucket)
#define CAP 18432        // per-bucket capacity (mean 16384, 16-sigma slack)

typedef __attribute__((ext_vector_type(8))) short short8;   // bf16x8 frag (4 VGPRs)
typedef __attribute__((ext_vector_type(4))) float floatx4;  // fp32x4 acc

__device__ inline short bfr(float f) {   // fp32 -> bf16 bits, round-nearest-even
    unsigned u = __float_as_uint(f);
    u += 0x7fffu + ((u >> 16) & 1u);
    return (short)(u >> 16);
}

// ---------------------------------------------------------------------------
// One-time: repack W (128x64 fp32) into bf16 MFMA B-fragments.
// Frag f = kt*4+nt; lane l holds B[k = kt*32 + (l>>4)*8 + j][n = nt*16 + (l&15)]
// stored contiguously (short8 per lane) for coalesced dwordx4 loads.
// ---------------------------------------------------------------------------
__global__ void k_prep(const float* __restrict__ W, short* __restrict__ wfrag)
{
    int idx = blockIdx.x * 256 + threadIdx.x;
    if (idx >= 1024) return;
    int f = idx >> 6, l = idx & 63;
    int kt = f >> 2, nt = f & 3;
    int k0 = kt * 32 + (l >> 4) * 8;
    int n = nt * 16 + (l & 15);
#pragma unroll
    for (int j = 0; j < 8; ++j)
        wfrag[idx * 8 + j] = bfr(W[(k0 + j) * HID + n]);
}

// ---------------------------------------------------------------------------
// h = x @ W via mfma_f32_16x16x32_bf16. Block 256 = 4 waves; each wave does
// 2 M-tiles of 16 rows (32 rows/wave, 128/block). A-frags loaded straight
// from global in fragment order (lane row = l&15, k = quad*8+j -> 32 B/lane,
// whole 128-B segments per row). B-frags preloaded once (16 x dwordx4).
// Epilogue: h store (bf16) + a_src/a_dst via intra-quad shfl_xor reduction.
// C-layout: col = lane&15, row = quad*4 + reg  [m89].
// ---------------------------------------------------------------------------
__global__ __launch_bounds__(256) void k_gemm(
    const float* __restrict__ x, const short8* __restrict__ wfrag,
    const float* __restrict__ att_src, const float* __restrict__ att_dst,
    short* __restrict__ h, float* __restrict__ a_src,
    float* __restrict__ a_dst, int N)
{
    const int t = threadIdx.x;
    const int lane = t & 63;
    const int wv = t >> 6;
    const int l15 = lane & 15;
    const int quad = lane >> 4;

    short8 bf[16];
#pragma unroll
    for (int f = 0; f < 16; ++f) bf[f] = wfrag[f * 64 + lane];

    float as4[4], ad4[4];
#pragma unroll
    for (int nt = 0; nt < 4; ++nt) {
        as4[nt] = att_src[nt * 16 + l15];
        ad4[nt] = att_dst[nt * 16 + l15];
    }

    const int rowbase = blockIdx.x * 128 + wv * 32;

#pragma unroll
    for (int mt = 0; mt < 2; ++mt) {
        const int m0 = rowbase + mt * 16;
        const int rowa = m0 + l15;
        const int rowc = rowa < N ? rowa : N - 1;   // clamp loads
        const float* xp = x + (size_t)rowc * IN_CH + quad * 8;

        short8 af[4];
#pragma unroll
        for (int kt = 0; kt < 4; ++kt) {
            float4 p0 = *(const float4*)(xp + kt * 32);
            float4 p1 = *(const float4*)(xp + kt * 32 + 4);
            short8 a;
            a[0] = bfr(p0.x); a[1] = bfr(p0.y); a[2] = bfr(p0.z); a[3] = bfr(p0.w);
            a[4] = bfr(p1.x); a[5] = bfr(p1.y); a[6] = bfr(p1.z); a[7] = bfr(p1.w);
            af[kt] = a;
        }

        floatx4 acc[4];
#pragma unroll
        for (int nt = 0; nt < 4; ++nt) acc[nt] = (floatx4){0.f, 0.f, 0.f, 0.f};
#pragma unroll
        for (int kt = 0; kt < 4; ++kt)
#pragma unroll
            for (int nt = 0; nt < 4; ++nt)
                acc[nt] = __builtin_amdgcn_mfma_f32_16x16x32_bf16(
                    af[kt], bf[kt * 4 + nt], acc[nt], 0, 0, 0);

        // epilogue: rows m0 + quad*4 + r
#pragma unroll
        for (int r = 0; r < 4; ++r) {
            const int row = m0 + quad * 4 + r;
            const bool ok = row < N;
            if (ok) {
#pragma unroll
                for (int nt = 0; nt < 4; ++nt)
                    h[(size_t)row * HID + nt * 16 + l15] = bfr(acc[nt][r]);
            }
            float ps = acc[0][r] * as4[0] + acc[1][r] * as4[1] +
                       acc[2][r] * as4[2] + acc[3][r] * as4[3];
            float pd = acc[0][r] * ad4[0] + acc[1][r] * ad4[1] +
                       acc[2][r] * ad4[2] + acc[3][r] * ad4[3];
#pragma unroll
            for (int m2 = 1; m2 < 16; m2 <<= 1) {
                ps += __shfl_xor(ps, m2, 64);
                pd += __shfl_xor(pd, m2, 64);
            }
            if (ok && l15 == 0) { a_src[row] = ps; a_dst[row] = pd; }
        }
    }
}

// ---------------------------------------------------------------------------
// Bucket pass: bin edges by dst>>9 into per-bucket append regions. Packed
// payload: s | (dst&511)<<17 (s < 2^17).
// ---------------------------------------------------------------------------
__global__ __launch_bounds__(256) void k_binB(
    const int* __restrict__ ei, int* __restrict__ g_cursor,
    int* __restrict__ pairs, int E, int nb)
{
    __shared__ int hist[256];
    __shared__ int base[256];
    const int t = threadIdx.x;
    hist[t] = 0;
    __syncthreads();

    int s[16], d[16];
    const int4* s4 = (const int4*)ei;
    const int4* d4 = (const int4*)(ei + E);
    const int E4 = E >> 2;
    const int q0 = blockIdx.x * 1024;
#pragma unroll
    for (int i = 0; i < 4; ++i) {
        int q = q0 + i * 256 + t;
        int4 sv = make_int4(0, 0, 0, 0);
        int4 dv = make_int4(-1, -1, -1, -1);
        if (q < E4) { sv = s4[q]; dv = d4[q]; }
        s[4 * i + 0] = sv.x; s[4 * i + 1] = sv.y; s[4 * i + 2] = sv.z; s[4 * i + 3] = sv.w;
        d[4 * i + 0] = dv.x; d[4 * i + 1] = dv.y; d[4 * i + 2] = dv.z; d[4 * i + 3] = dv.w;
    }
#pragma unroll
    for (int i = 0; i < 16; ++i)
        if (d[i] >= 0) atomicAdd(&hist[d[i] >> BSH], 1);
    __syncthreads();

    if (t < nb) base[t] = atomicAdd(&g_cursor[t], hist[t]);
    __syncthreads();
    hist[t] = 0;
    __syncthreads();

#pragma unroll
    for (int i = 0; i < 16; ++i) {
        if (d[i] < 0) continue;
        int b = d[i] >> BSH;
        int l = atomicAdd(&hist[b], 1);
        int pos = base[b] + l;
        if (pos < CAP)
            pairs[b * CAP + pos] = s[i] | ((d[i] & 511) << 17);
    }
}

// exclusive scan of bucket counts (nb <= 256), single block
__global__ __launch_bounds__(256) void k_bscan(
    const int* __restrict__ g_cursor, int* __restrict__ bucket_base, int nb)
{
    __shared__ int sh[256];
    const int t = threadIdx.x;
    int v = (t < nb) ? g_cursor[t] : 0;
    sh[t] = v;
    __syncthreads();
    for (int off = 1; off < 256; off <<= 1) {
        int u = (t >= off) ? sh[t - off] : 0;
        __syncthreads();
        sh[t] += u;
        __syncthreads();
    }
    if (t < nb) bucket_base[t] = sh[t] - v;
}

// ---------------------------------------------------------------------------
// Per-bucket finalize: one block per bucket. LDS per-dst histogram (512) ->
// block scan -> row_start/cnt -> scatter csr_src into an L2-local window.
// ---------------------------------------------------------------------------
__global__ __launch_bounds__(512) void k_binC(
    const int* __restrict__ pairs, const int* __restrict__ g_cursor,
    const int* __restrict__ bucket_base,
    int* __restrict__ row_start, int* __restrict__ cnt,
    int* __restrict__ csr_src, int N)
{
    __shared__ int h0[512];
    __shared__ int hs[512];
    __shared__ int cur[512];
    const int t = threadIdx.x;
    const int b = blockIdx.x;
    const int d0 = b << BSH;
    const int m = g_cursor[b];
    const int basec = bucket_base[b];
    const int* pb = pairs + b * CAP;

    h0[t] = 0;
    __syncthreads();
    for (int i = t; i < m; i += 512)
        atomicAdd(&h0[pb[i] >> 17], 1);
    __syncthreads();

    hs[t] = h0[t];
    __syncthreads();
    for (int off = 1; off < 512; off <<= 1) {
        int u = (t >= off) ? hs[t - off] : 0;
        __syncthreads();
        hs[t] += u;
        __syncthreads();
    }
    const int excl = hs[t] - h0[t];
    cur[t] = basec + excl;
    const int dd = d0 + t;
    if (dd < N) { row_start[dd] = basec + excl; cnt[dd] = h0[t]; }
    __syncthreads();

    for (int i = t; i < m; i += 512) {
        int p = pb[i];
        int pos = atomicAdd(&cur[p >> 17], 1);
        csr_src[pos] = p & 0x1FFFF;
    }
}

// ---------------------------------------------------------------------------
// wave-per-dst online aggregation, 8 edges per inner iteration.
// lane = eighth q (edge j+q, q=lane>>3) x chunk i8 (lane&7). Each lane loads
// uint4 = 8 bf16 channels; 8 lanes cover a full 128-B h row (one cache line),
// 64 lanes = 8 rows/iter. vs previous dwordx2/4-row version: half the VMEM
// instructions, half the shuffles, 2x bytes per load, unroll 4 -> 4 x 16 B
// gathers in flight per wave. Cross-q reduce (xor 8/16/32) at end.
// ---------------------------------------------------------------------------
__global__ __launch_bounds__(256) void k_agg(
    const __hip_bfloat16* __restrict__ h, const float* __restrict__ a_src,
    const float* __restrict__ a_dst, const float* __restrict__ bias,
    const int* __restrict__ row_start, const int* __restrict__ cnt,
    const int* __restrict__ csr_src,
    float* __restrict__ out, float* __restrict__ inv_s, int N)
{
    const int wave = threadIdx.x >> 6;
    const int lane = threadIdx.x & 63;
    const int d = blockIdx.x * 4 + wave;
    if (d >= N) return;

    const int q  = lane >> 3;   // which row within the group of 8
    const int i8 = lane & 7;    // which 16-B chunk of the 128-B row

    const float ad = a_dst[d];
    const int start = row_start[d];
    const int n = cnt[d];
    const int end = start + n;

    const uint4* h4 = (const uint4*)h;   // row = 8 x uint4

    float psum = 0.f;
    float acc[8];
#pragma unroll
    for (int c = 0; c < 8; ++c) acc[c] = 0.f;

    for (int b = start; b < end; b += 64) {
        int idx = b + lane;
        int s = 0;
        float e = 0.f;
        if (idx < end) {
            s = csr_src[idx];
            float v = a_src[s] + ad;
            v = v > 0.f ? v : NEG_SLOPE * v;
            e = __expf(v);
            psum += e;
        }
        const int m = min(64, end - b);
#pragma unroll 4
        for (int j = 0; j < m; j += 8) {
            const int jq = j + q;
            const int sj = __shfl(s, jq, 64);       // lanes past end: s=0,e=0
            const float ej = __shfl(e, jq, 64);     // -> harmless row-0 load
            uint4 u = h4[(size_t)sj * 8 + i8];
            acc[0] = fmaf(ej, __uint_as_float(u.x << 16),          acc[0]);
            acc[1] = fmaf(ej, __uint_as_float(u.x & 0xffff0000u),  acc[1]);
            acc[2] = fmaf(ej, __uint_as_float(u.y << 16),          acc[2]);
            acc[3] = fmaf(ej, __uint_as_float(u.y & 0xffff0000u),  acc[3]);
            acc[4] = fmaf(ej, __uint_as_float(u.z << 16),          acc[4]);
            acc[5] = fmaf(ej, __uint_as_float(u.z & 0xffff0000u),  acc[5]);
            acc[6] = fmaf(ej, __uint_as_float(u.w << 16),          acc[6]);
            acc[7] = fmaf(ej, __uint_as_float(u.w & 0xffff0000u),  acc[7]);
        }
    }

#pragma unroll
    for (int m2 = 32; m2 > 0; m2 >>= 1) psum += __shfl_xor(psum, m2, 64);

    float vs = a_src[d] + ad;
    vs = vs > 0.f ? vs : NEG_SLOPE * vs;
    const float eself = __expf(vs);
    const float inv = 1.0f / (psum + eself);
    if (lane == 0) inv_s[d] = inv;

    // reduce across the 8 q-groups (lane bits 3,4,5)
#pragma unroll
    for (int c = 0; c < 8; ++c) {
        acc[c] += __shfl_xor(acc[c], 8, 64);
        acc[c] += __shfl_xor(acc[c], 16, 64);
        acc[c] += __shfl_xor(acc[c], 32, 64);
    }

    if (q == 0) {   // lanes 0..7 write the 64-ch output row, 32 B each
        uint4 u = h4[(size_t)d * 8 + i8];
        float hc[8];
        hc[0] = __uint_as_float(u.x << 16);
        hc[1] = __uint_as_float(u.x & 0xffff0000u);
        hc[2] = __uint_as_float(u.y << 16);
        hc[3] = __uint_as_float(u.y & 0xffff0000u);
        hc[4] = __uint_as_float(u.z << 16);
        hc[5] = __uint_as_float(u.z & 0xffff0000u);
        hc[6] = __uint_as_float(u.w << 16);
        hc[7] = __uint_as_float(u.w & 0xffff0000u);
        float4 b0 = ((const float4*)bias)[2 * i8];
        float4 b1 = ((const float4*)bias)[2 * i8 + 1];
        float4 o0, o1;
        o0.x = fmaf(eself, hc[0], acc[0]) * inv + b0.x;
        o0.y = fmaf(eself, hc[1], acc[1]) * inv + b0.y;
        o0.z = fmaf(eself, hc[2], acc[2]) * inv + b0.z;
        o0.w = fmaf(eself, hc[3], acc[3]) * inv + b0.w;
        o1.x = fmaf(eself, hc[4], acc[4]) * inv + b1.x;
        o1.y = fmaf(eself, hc[5], acc[5]) * inv + b1.y;
        o1.z = fmaf(eself, hc[6], acc[6]) * inv + b1.z;
        o1.w = fmaf(eself, hc[7], acc[7]) * inv + b1.w;
        float* op = out + (size_t)d * HID + 8 * i8;
        *(float4*)op       = o0;
        *(float4*)(op + 4) = o1;
    }
}

// ---------------------------------------------------------------------------
// edge-order alpha: coalesced write; random 4B gathers into 400 KB L2 tables.
// ---------------------------------------------------------------------------
__global__ void k_alpha(const int* __restrict__ ei,
                        const float* __restrict__ a_src,
                        const float* __restrict__ a_dst,
                        const float* __restrict__ inv_s,
                        float* __restrict__ out_alpha, int E, int N)
{
    int e = blockIdx.x * 256 + threadIdx.x;
    if (e >= E + N) return;
    int s, d;
    if (e < E) { s = ei[e]; d = ei[E + e]; }
    else       { s = e - E; d = s; }
    float v = a_src[s] + a_dst[d];
    v = v > 0.f ? v : NEG_SLOPE * v;
    out_alpha[e] = __expf(v) * inv_s[d];
}

// ---------------------------------------------------------------------------
extern "C" void kernel_launch(void* const* d_in, const int* in_sizes, int n_in,
                              void* d_out, int out_size, void* d_ws, size_t ws_size,
                              hipStream_t stream)
{
    (void)n_in; (void)out_size; (void)ws_size;
    const float* x       = (const float*)d_in[0];
    const int*   ei      = (const int*)d_in[1];
    const float* W       = (const float*)d_in[2];
    const float* att_src = (const float*)d_in[3];
    const float* att_dst = (const float*)d_in[4];
    const float* bias    = (const float*)d_in[5];

    const int N = in_sizes[0] / IN_CH;   // 100000
    const int E = in_sizes[1] / 2;       // 3200000
    const int T = E + N;
    const int nb = (N + 511) >> BSH;     // 196 buckets

    // workspace layout
    __hip_bfloat16* h = (__hip_bfloat16*)d_ws;     // N*HID bf16 (12.8 MB)
    float* a_src_d = (float*)(h + (size_t)N * HID);// N
    float* a_dst_d = a_src_d + N;                  // N
    float* inv_s   = a_dst_d + N;                  // N
    int* row_start = (int*)(inv_s + N);            // N
    int* cnt       = row_start + N;                // N
    int* g_cursor  = cnt + N;                      // 256
    int* bucket_b  = g_cursor + 256;               // 256
    short* wfrag   = (short*)(bucket_b + 256);     // 8192 shorts (16 KB)
    int* pairs     = (int*)(wfrag + 8192);         // nb*CAP
    int* csr_src   = pairs + (size_t)nb * CAP;     // E

    float* out       = (float*)d_out;              // N*HID
    float* out_alpha = out + (size_t)N * HID;      // T

    k_prep<<<4, 256, 0, stream>>>(W, wfrag);
    k_gemm<<<(N + 127) / 128, 256, 0, stream>>>(x, (const short8*)wfrag,
                                                att_src, att_dst,
                                                (short*)h, a_src_d, a_dst_d, N);
    hipMemsetAsync(g_cursor, 0, 256 * sizeof(int), stream);
    k_binB<<<(E / 4 + 1023) / 1024, 256, 0, stream>>>(ei, g_cursor, pairs, E, nb);
    k_bscan<<<1, 256, 0, stream>>>(g_cursor, bucket_b, nb);
    k_binC<<<nb, 512, 0, stream>>>(pairs, g_cursor, bucket_b,
                                   row_start, cnt, csr_src, N);
    k_agg<<<(N + 3) / 4, 256, 0, stream>>>(h, a_src_d, a_dst_d, bias,
                                           row_start, cnt, csr_src,
                                           out, inv_s, N);
    k_alpha<<<(T + 255) / 256, 256, 0, stream>>>(ei, a_src_d, a_dst_d, inv_s,
                                                 out_alpha, E, N);
}

// Round 2
// 273.298 us; speedup vs baseline: 1.1533x; 1.0958x over previous
//
#include <hip/hip_runtime.h>
#include <hip/hip_bf16.h>

#define IN_CH 128
#define HID 64
#define NEG_SLOPE 0.2f
#define BSH 9            // bucket = dst >> 9  (512 dsts per bucket)
#define CAP 18432        // per-bucket capacity (mean 16384, 16-sigma slack)

typedef __attribute__((ext_vector_type(8))) short short8;   // bf16x8 frag (4 VGPRs)
typedef __attribute__((ext_vector_type(4))) float floatx4;  // fp32x4 acc

__device__ inline short bfr(float f) {   // fp32 -> bf16 bits, round-nearest-even
    unsigned u = __float_as_uint(f);
    u += 0x7fffu + ((u >> 16) & 1u);
    return (short)(u >> 16);
}

// ---------------------------------------------------------------------------
// One-time: repack W (128x64 fp32) into bf16 MFMA B-fragments; block 0 also
// zeroes g_cursor (replaces a standalone hipMemsetAsync dispatch).
// ---------------------------------------------------------------------------
__global__ void k_prep(const float* __restrict__ W, short* __restrict__ wfrag,
                       int* __restrict__ g_cursor)
{
    if (blockIdx.x == 0) g_cursor[threadIdx.x] = 0;
    int idx = blockIdx.x * 256 + threadIdx.x;
    if (idx >= 1024) return;
    int f = idx >> 6, l = idx & 63;
    int kt = f >> 2, nt = f & 3;
    int k0 = kt * 32 + (l >> 4) * 8;
    int n = nt * 16 + (l & 15);
#pragma unroll
    for (int j = 0; j < 8; ++j)
        wfrag[idx * 8 + j] = bfr(W[(k0 + j) * HID + n]);
}

// ---------------------------------------------------------------------------
// h = x @ W via mfma_f32_16x16x32_bf16. Block 256 = 4 waves; each wave does
// 2 M-tiles of 16 rows. C-layout: col = lane&15, row = quad*4 + reg  [m89].
// ---------------------------------------------------------------------------
__global__ __launch_bounds__(256) void k_gemm(
    const float* __restrict__ x, const short8* __restrict__ wfrag,
    const float* __restrict__ att_src, const float* __restrict__ att_dst,
    short* __restrict__ h, float* __restrict__ a_src,
    float* __restrict__ a_dst, int N)
{
    const int t = threadIdx.x;
    const int lane = t & 63;
    const int wv = t >> 6;
    const int l15 = lane & 15;
    const int quad = lane >> 4;

    short8 bf[16];
#pragma unroll
    for (int f = 0; f < 16; ++f) bf[f] = wfrag[f * 64 + lane];

    float as4[4], ad4[4];
#pragma unroll
    for (int nt = 0; nt < 4; ++nt) {
        as4[nt] = att_src[nt * 16 + l15];
        ad4[nt] = att_dst[nt * 16 + l15];
    }

    const int rowbase = blockIdx.x * 128 + wv * 32;

#pragma unroll
    for (int mt = 0; mt < 2; ++mt) {
        const int m0 = rowbase + mt * 16;
        const int rowa = m0 + l15;
        const int rowc = rowa < N ? rowa : N - 1;   // clamp loads
        const float* xp = x + (size_t)rowc * IN_CH + quad * 8;

        short8 af[4];
#pragma unroll
        for (int kt = 0; kt < 4; ++kt) {
            float4 p0 = *(const float4*)(xp + kt * 32);
            float4 p1 = *(const float4*)(xp + kt * 32 + 4);
            short8 a;
            a[0] = bfr(p0.x); a[1] = bfr(p0.y); a[2] = bfr(p0.z); a[3] = bfr(p0.w);
            a[4] = bfr(p1.x); a[5] = bfr(p1.y); a[6] = bfr(p1.z); a[7] = bfr(p1.w);
            af[kt] = a;
        }

        floatx4 acc[4];
#pragma unroll
        for (int nt = 0; nt < 4; ++nt) acc[nt] = (floatx4){0.f, 0.f, 0.f, 0.f};
#pragma unroll
        for (int kt = 0; kt < 4; ++kt)
#pragma unroll
            for (int nt = 0; nt < 4; ++nt)
                acc[nt] = __builtin_amdgcn_mfma_f32_16x16x32_bf16(
                    af[kt], bf[kt * 4 + nt], acc[nt], 0, 0, 0);

        // epilogue: rows m0 + quad*4 + r
#pragma unroll
        for (int r = 0; r < 4; ++r) {
            const int row = m0 + quad * 4 + r;
            const bool ok = row < N;
            if (ok) {
#pragma unroll
                for (int nt = 0; nt < 4; ++nt)
                    h[(size_t)row * HID + nt * 16 + l15] = bfr(acc[nt][r]);
            }
            float ps = acc[0][r] * as4[0] + acc[1][r] * as4[1] +
                       acc[2][r] * as4[2] + acc[3][r] * as4[3];
            float pd = acc[0][r] * ad4[0] + acc[1][r] * ad4[1] +
                       acc[2][r] * ad4[2] + acc[3][r] * ad4[3];
#pragma unroll
            for (int m2 = 1; m2 < 16; m2 <<= 1) {
                ps += __shfl_xor(ps, m2, 64);
                pd += __shfl_xor(pd, m2, 64);
            }
            if (ok && l15 == 0) { a_src[row] = ps; a_dst[row] = pd; }
        }
    }
}

// ---------------------------------------------------------------------------
// Bucket pass: bin edges by dst>>9 into per-bucket append regions. Packed
// payload: s | (dst&511)<<17 (s < 2^17).
// ---------------------------------------------------------------------------
__global__ __launch_bounds__(256) void k_binB(
    const int* __restrict__ ei, int* __restrict__ g_cursor,
    int* __restrict__ pairs, int E, int nb)
{
    __shared__ int hist[256];
    __shared__ int base[256];
    const int t = threadIdx.x;
    hist[t] = 0;
    __syncthreads();

    int s[16], d[16];
    const int4* s4 = (const int4*)ei;
    const int4* d4 = (const int4*)(ei + E);
    const int E4 = E >> 2;
    const int q0 = blockIdx.x * 1024;
#pragma unroll
    for (int i = 0; i < 4; ++i) {
        int q = q0 + i * 256 + t;
        int4 sv = make_int4(0, 0, 0, 0);
        int4 dv = make_int4(-1, -1, -1, -1);
        if (q < E4) { sv = s4[q]; dv = d4[q]; }
        s[4 * i + 0] = sv.x; s[4 * i + 1] = sv.y; s[4 * i + 2] = sv.z; s[4 * i + 3] = sv.w;
        d[4 * i + 0] = dv.x; d[4 * i + 1] = dv.y; d[4 * i + 2] = dv.z; d[4 * i + 3] = dv.w;
    }
#pragma unroll
    for (int i = 0; i < 16; ++i)
        if (d[i] >= 0) atomicAdd(&hist[d[i] >> BSH], 1);
    __syncthreads();

    if (t < nb) base[t] = atomicAdd(&g_cursor[t], hist[t]);
    __syncthreads();
    hist[t] = 0;
    __syncthreads();

#pragma unroll
    for (int i = 0; i < 16; ++i) {
        if (d[i] < 0) continue;
        int b = d[i] >> BSH;
        int l = atomicAdd(&hist[b], 1);
        int pos = base[b] + l;
        if (pos < CAP)
            pairs[b * CAP + pos] = s[i] | ((d[i] & 511) << 17);
    }
}

// ---------------------------------------------------------------------------
// Per-bucket finalize: one block per bucket. Redundant per-block scan of the
// bucket counts replaces the standalone k_bscan dispatch. Then LDS per-dst
// histogram (512) -> block scan -> row_start/cnt -> scatter csr_src.
// ---------------------------------------------------------------------------
__global__ __launch_bounds__(512) void k_binC(
    const int* __restrict__ pairs, const int* __restrict__ g_cursor,
    int* __restrict__ row_start, int* __restrict__ cnt,
    int* __restrict__ csr_src, int N, int nb)
{
    __shared__ int h0[512];
    __shared__ int hs[512];
    __shared__ int cur[512];
    __shared__ int sbase;
    const int t = threadIdx.x;
    const int b = blockIdx.x;
    const int d0 = b << BSH;
    const int m = g_cursor[b];
    const int* pb = pairs + b * CAP;

    // exclusive bucket-base via redundant in-block scan (replaces k_bscan)
    int bv = (t < nb) ? g_cursor[t] : 0;
    hs[t] = bv;
    __syncthreads();
    for (int off = 1; off < 512; off <<= 1) {
        int u = (t >= off) ? hs[t - off] : 0;
        __syncthreads();
        hs[t] += u;
        __syncthreads();
    }
    if (t == b) sbase = hs[t] - bv;
    h0[t] = 0;
    __syncthreads();
    const int basec = sbase;

    for (int i = t; i < m; i += 512)
        atomicAdd(&h0[pb[i] >> 17], 1);
    __syncthreads();

    hs[t] = h0[t];
    __syncthreads();
    for (int off = 1; off < 512; off <<= 1) {
        int u = (t >= off) ? hs[t - off] : 0;
        __syncthreads();
        hs[t] += u;
        __syncthreads();
    }
    const int excl = hs[t] - h0[t];
    cur[t] = basec + excl;
    const int dd = d0 + t;
    if (dd < N) { row_start[dd] = basec + excl; cnt[dd] = h0[t]; }
    __syncthreads();

    for (int i = t; i < m; i += 512) {
        int p = pb[i];
        int pos = atomicAdd(&cur[p >> 17], 1);
        csr_src[pos] = p & 0x1FFFF;
    }
}

// ---------------------------------------------------------------------------
// Aggregation: TWO dsts per wave, interleaved -> 8 gather loads in flight per
// wave (vs 4), overlapping both shfl->load->fma chains. Lane = q (lane>>3) x
// chunk i8 (lane&7); uint4 = 8 bf16 ch, 8 lanes/row, 8 rows per dst-stream
// per iter. Epilogue: partials via pad-9 LDS scratch (2-way bank alias only),
// reader lane t owns output channel ch==lane -> coalesced 4B stores. Replaces
// the 48-shuffle xor-tree. adi = packed (a_dst, inv_s) for k_alpha.
// ---------------------------------------------------------------------------
__global__ __launch_bounds__(256) void k_agg(
    const __hip_bfloat16* __restrict__ h, const float* __restrict__ a_src,
    const float* __restrict__ a_dst, const float* __restrict__ bias,
    const int* __restrict__ row_start, const int* __restrict__ cnt,
    const int* __restrict__ csr_src,
    float* __restrict__ out, float2* __restrict__ adi, int N)
{
    __shared__ float red[4][2][576];   // [wave][dst][lane*9+c], pad 9
    const int wave = threadIdx.x >> 6;
    const int lane = threadIdx.x & 63;
    const int d0 = blockIdx.x * 8 + wave * 2;
    if (d0 >= N) return;
    const int d1 = d0 + 1;
    const bool has1 = d1 < N;

    const int q  = lane >> 3;   // row slot within group of 8
    const int i8 = lane & 7;    // 16-B chunk of the 128-B row

    const float ad0 = a_dst[d0];
    const float ad1 = has1 ? a_dst[d1] : 0.f;
    const int st0 = row_start[d0];
    const int n0  = cnt[d0];
    const int en0 = st0 + n0;
    const int st1 = has1 ? row_start[d1] : 0;
    const int n1  = has1 ? cnt[d1] : 0;
    const int en1 = st1 + n1;

    const uint4* h4 = (const uint4*)h;

    float ps0 = 0.f, ps1 = 0.f;
    float ac0[8], ac1[8];
#pragma unroll
    for (int c = 0; c < 8; ++c) { ac0[c] = 0.f; ac1[c] = 0.f; }

    const int nbt0 = (n0 + 63) >> 6;
    const int nbt1 = (n1 + 63) >> 6;
    const int nbm = nbt0 > nbt1 ? nbt0 : nbt1;

    int b0 = st0, b1 = st1;
    for (int it = 0; it < nbm; ++it, b0 += 64, b1 += 64) {
        int s0v = 0, s1v = 0;
        float e0 = 0.f, e1 = 0.f;
        const int idx0 = b0 + lane;
        if (it < nbt0 && idx0 < en0) {
            s0v = csr_src[idx0];
            float v = a_src[s0v] + ad0;
            v = v > 0.f ? v : NEG_SLOPE * v;
            e0 = __expf(v);
            ps0 += e0;
        }
        const int idx1 = b1 + lane;
        if (it < nbt1 && idx1 < en1) {
            s1v = csr_src[idx1];
            float v = a_src[s1v] + ad1;
            v = v > 0.f ? v : NEG_SLOPE * v;
            e1 = __expf(v);
            ps1 += e1;
        }
        const int m0 = (it < nbt0) ? min(64, en0 - b0) : 0;
        const int m1 = (it < nbt1) ? min(64, en1 - b1) : 0;
        const int mm = m0 > m1 ? m0 : m1;
#pragma unroll 4
        for (int j = 0; j < mm; j += 8) {
            const int jq = j + q;
            const int sj0 = __shfl(s0v, jq, 64);    // inactive slots: s=0,e=0
            const float ej0 = __shfl(e0, jq, 64);   // -> harmless row-0 load
            const int sj1 = __shfl(s1v, jq, 64);
            const float ej1 = __shfl(e1, jq, 64);
            uint4 u0 = h4[(size_t)sj0 * 8 + i8];
            uint4 u1 = h4[(size_t)sj1 * 8 + i8];
            ac0[0] = fmaf(ej0, __uint_as_float(u0.x << 16),         ac0[0]);
            ac0[1] = fmaf(ej0, __uint_as_float(u0.x & 0xffff0000u), ac0[1]);
            ac0[2] = fmaf(ej0, __uint_as_float(u0.y << 16),         ac0[2]);
            ac0[3] = fmaf(ej0, __uint_as_float(u0.y & 0xffff0000u), ac0[3]);
            ac0[4] = fmaf(ej0, __uint_as_float(u0.z << 16),         ac0[4]);
            ac0[5] = fmaf(ej0, __uint_as_float(u0.z & 0xffff0000u), ac0[5]);
            ac0[6] = fmaf(ej0, __uint_as_float(u0.w << 16),         ac0[6]);
            ac0[7] = fmaf(ej0, __uint_as_float(u0.w & 0xffff0000u), ac0[7]);
            ac1[0] = fmaf(ej1, __uint_as_float(u1.x << 16),         ac1[0]);
            ac1[1] = fmaf(ej1, __uint_as_float(u1.x & 0xffff0000u), ac1[1]);
            ac1[2] = fmaf(ej1, __uint_as_float(u1.y << 16),         ac1[2]);
            ac1[3] = fmaf(ej1, __uint_as_float(u1.y & 0xffff0000u), ac1[3]);
            ac1[4] = fmaf(ej1, __uint_as_float(u1.z << 16),         ac1[4]);
            ac1[5] = fmaf(ej1, __uint_as_float(u1.z & 0xffff0000u), ac1[5]);
            ac1[6] = fmaf(ej1, __uint_as_float(u1.w << 16),         ac1[6]);
            ac1[7] = fmaf(ej1, __uint_as_float(u1.w & 0xffff0000u), ac1[7]);
        }
    }

    // stash partials to LDS (wave-local scratch; same-wave DS ops are ordered)
    float* r0 = &red[wave][0][0];
    float* r1 = &red[wave][1][0];
#pragma unroll
    for (int c = 0; c < 8; ++c) r0[lane * 9 + c] = ac0[c];
#pragma unroll
    for (int c = 0; c < 8; ++c) r1[lane * 9 + c] = ac1[c];

    // psum reduce (overlaps LDS settle)
#pragma unroll
    for (int m2 = 32; m2 > 0; m2 >>= 1) {
        ps0 += __shfl_xor(ps0, m2, 64);
        ps1 += __shfl_xor(ps1, m2, 64);
    }

    float vs0 = a_src[d0] + ad0;
    vs0 = vs0 > 0.f ? vs0 : NEG_SLOPE * vs0;
    const float es0 = __expf(vs0);
    const float inv0 = 1.f / (ps0 + es0);
    float es1 = 0.f, inv1 = 0.f;
    if (has1) {
        float vs1 = a_src[d1] + ad1;
        vs1 = vs1 > 0.f ? vs1 : NEG_SLOPE * vs1;
        es1 = __expf(vs1);
        inv1 = 1.f / (ps1 + es1);
    }
    if (lane == 0) {
        adi[d0] = make_float2(ad0, inv0);
        if (has1) adi[d1] = make_float2(ad1, inv1);
    }

    // gather-reduce across the 8 q-groups: lane t owns channel ch == lane
    const int oi = lane >> 3, oc = lane & 7;
    float s0 = 0.f, s1 = 0.f;
#pragma unroll
    for (int qq = 0; qq < 8; ++qq) {
        s0 += r0[(qq * 8 + oi) * 9 + oc];
        s1 += r1[(qq * 8 + oi) * 9 + oc];
    }

    const ushort* hu = (const ushort*)h;
    const float bi = bias[lane];
    float hs0 = __uint_as_float(((unsigned)hu[(size_t)d0 * HID + lane]) << 16);
    out[(size_t)d0 * HID + lane] = fmaf(es0, hs0, s0) * inv0 + bi;
    if (has1) {
        float hs1 = __uint_as_float(((unsigned)hu[(size_t)d1 * HID + lane]) << 16);
        out[(size_t)d1 * HID + lane] = fmaf(es1, hs1, s1) * inv1 + bi;
    }
}

// ---------------------------------------------------------------------------
// edge-order alpha: coalesced write; adi packs (a_dst, inv_s) -> 2 random
// gathers per edge instead of 3.
// ---------------------------------------------------------------------------
__global__ void k_alpha(const int* __restrict__ ei,
                        const float* __restrict__ a_src,
                        const float2* __restrict__ adi,
                        float* __restrict__ out_alpha, int E, int N)
{
    int e = blockIdx.x * 256 + threadIdx.x;
    if (e >= E + N) return;
    int s, d;
    if (e < E) { s = ei[e]; d = ei[E + e]; }
    else       { s = e - E; d = s; }
    float2 av = adi[d];
    float v = a_src[s] + av.x;
    v = v > 0.f ? v : NEG_SLOPE * v;
    out_alpha[e] = __expf(v) * av.y;
}

// ---------------------------------------------------------------------------
extern "C" void kernel_launch(void* const* d_in, const int* in_sizes, int n_in,
                              void* d_out, int out_size, void* d_ws, size_t ws_size,
                              hipStream_t stream)
{
    (void)n_in; (void)out_size; (void)ws_size;
    const float* x       = (const float*)d_in[0];
    const int*   ei      = (const int*)d_in[1];
    const float* W       = (const float*)d_in[2];
    const float* att_src = (const float*)d_in[3];
    const float* att_dst = (const float*)d_in[4];
    const float* bias    = (const float*)d_in[5];

    const int N = in_sizes[0] / IN_CH;   // 100000
    const int E = in_sizes[1] / 2;       // 3200000
    const int T = E + N;
    const int nb = (N + 511) >> BSH;     // 196 buckets

    // workspace layout
    __hip_bfloat16* h = (__hip_bfloat16*)d_ws;     // N*HID bf16 (12.8 MB)
    float* a_src_d = (float*)(h + (size_t)N * HID);// N
    float* a_dst_d = a_src_d + N;                  // N
    float2* adi    = (float2*)(a_dst_d + N);       // N float2 (a_dst, inv_s)
    int* row_start = (int*)(adi + N);              // N
    int* cnt       = row_start + N;                // N
    int* g_cursor  = cnt + N;                      // 256
    short* wfrag   = (short*)(g_cursor + 256);     // 8192 shorts (16 KB)
    int* pairs     = (int*)(wfrag + 8192);         // nb*CAP
    int* csr_src   = pairs + (size_t)nb * CAP;     // E

    float* out       = (float*)d_out;              // N*HID
    float* out_alpha = out + (size_t)N * HID;      // T

    k_prep<<<4, 256, 0, stream>>>(W, wfrag, g_cursor);
    k_gemm<<<(N + 127) / 128, 256, 0, stream>>>(x, (const short8*)wfrag,
                                                att_src, att_dst,
                                                (short*)h, a_src_d, a_dst_d, N);
    k_binB<<<(E / 4 + 1023) / 1024, 256, 0, stream>>>(ei, g_cursor, pairs, E, nb);
    k_binC<<<nb, 512, 0, stream>>>(pairs, g_cursor,
                                   row_start, cnt, csr_src, N, nb);
    k_agg<<<(N + 7) / 8, 256, 0, stream>>>(h, a_src_d, a_dst_d, bias,
                                           row_start, cnt, csr_src,
                                           out, adi, N);
    k_alpha<<<(T + 255) / 256, 256, 0, stream>>>(ei, a_src_d, adi,
                                                 out_alpha, E, N);
}